// Round 2
// baseline (580.492 us; speedup 1.0000x reference)
//
#include <hip/hip_runtime.h>
#include <hip/hip_bf16.h>
#include <stdint.h>
#include <math.h>

#define D_MODEL 1024
#define NH 16
#define HD 64
#define BATCH 4
#define SEQ 2048
#define MTOT (BATCH*SEQ)   // 8192
#define NBH (BATCH*NH)     // 64

typedef __attribute__((ext_vector_type(8))) short short8;   // 8 bf16
typedef __attribute__((ext_vector_type(4))) short short4v;  // 4 bf16
typedef __attribute__((ext_vector_type(4))) float f32x4;

static __device__ __forceinline__ unsigned short f2bf(float f) {
  union { float f; unsigned u; } v; v.f = f;
  unsigned r = v.u + 0x7FFFu + ((v.u >> 16) & 1u);   // RNE
  return (unsigned short)(r >> 16);
}

#define GLOAD16(g, l) __builtin_amdgcn_global_load_lds( \
    (const __attribute__((address_space(1))) unsigned int*)(g), \
    (__attribute__((address_space(3))) unsigned int*)(l), 16, 0, 0)

// ---------------------------------------------------------------------------
// K0: convert x and weights to bf16, build RoPE tables
// ---------------------------------------------------------------------------
__global__ __launch_bounds__(256) void k_prep(
    const float* __restrict__ x, const float* __restrict__ wq,
    const float* __restrict__ wk, const float* __restrict__ wv,
    const float* __restrict__ wo,
    unsigned short* __restrict__ xb, unsigned short* __restrict__ wb,
    float* __restrict__ cosT, float* __restrict__ sinT) {
  long i = (long)blockIdx.x * 256 + threadIdx.x;
  const long NX = (long)MTOT * D_MODEL;
  const long NW = (long)D_MODEL * D_MODEL;
  if (i < NX) { xb[i] = f2bf(x[i]); return; }
  i -= NX;
  if (i < NW) { wb[i] = f2bf(wq[i]); return; }
  i -= NW;
  if (i < NW) { wb[NW + i] = f2bf(wk[i]); return; }
  i -= NW;
  if (i < NW) { wb[2 * NW + i] = f2bf(wv[i]); return; }
  i -= NW;
  if (i < NW) { wb[3 * NW + i] = f2bf(wo[i]); return; }
  i -= NW;
  if (i < (long)SEQ * (HD / 2)) {
    int t = (int)(i >> 5), j = (int)(i & 31);
    float freq = 1.0f / powf(10000.0f, (float)j * (1.0f / 32.0f));
    float ang = (float)t * freq;
    cosT[i] = cosf(ang);
    sinT[i] = sinf(ang);
  }
}

// ---------------------------------------------------------------------------
// GEMM: C[m][n] = sum_k A[m][k] * Bw[n][k]
// EPI=0 (QKV): RoPE fused for q/k, scatter to q/k [bh][t][d]; V stored
// transposed to vt [bh][d][t].  EPI=1: fp32 out [m][n].
// ---------------------------------------------------------------------------
template<int EPI>
__global__ __launch_bounds__(256) void k_gemm(
    const unsigned short* __restrict__ A, const unsigned short* __restrict__ Bw,
    unsigned short* __restrict__ q, unsigned short* __restrict__ k2,
    unsigned short* __restrict__ vt,
    const float* __restrict__ cosT, const float* __restrict__ sinT,
    float* __restrict__ outf) {
  __shared__ __align__(16) unsigned short As[128 * 32];
  __shared__ __align__(16) unsigned short Bs[128 * 32];
  const int tid = threadIdx.x;
  const int wid = tid >> 6, lane = tid & 63;
  const int l15 = lane & 15, lq = lane >> 4;
  const int m0 = blockIdx.x * 128, n0 = blockIdx.y * 128;
  const int wm = (wid >> 1) * 64, wn = (wid & 1) * 64;

  const f32x4 fz = {0.f, 0.f, 0.f, 0.f};
  f32x4 acc[4][4];
#pragma unroll
  for (int i = 0; i < 4; ++i)
#pragma unroll
    for (int j = 0; j < 4; ++j) acc[i][j] = fz;

  const int srow = wid * 16 + (lane >> 2);
  const int scol = (lane & 3) * 8;
  const unsigned short* Ag = A + (long)(m0 + srow) * D_MODEL + scol;
  const unsigned short* Bg = Bw + (long)(n0 + srow) * D_MODEL + scol;

  for (int k0 = 0; k0 < D_MODEL; k0 += 32) {
    GLOAD16(Ag + k0, As + wid * 512);
    GLOAD16(Ag + k0 + 64 * D_MODEL, As + 2048 + wid * 512);
    GLOAD16(Bg + k0, Bs + wid * 512);
    GLOAD16(Bg + k0 + 64 * D_MODEL, Bs + 2048 + wid * 512);
    __syncthreads();

    short8 af[4], bf[4];
#pragma unroll
    for (int i = 0; i < 4; ++i) {
      af[i] = *(const short8*)(As + (wm + i * 16 + l15) * 32 + lq * 8);
      bf[i] = *(const short8*)(Bs + (wn + i * 16 + l15) * 32 + lq * 8);
    }
#pragma unroll
    for (int i = 0; i < 4; ++i)
#pragma unroll
      for (int j = 0; j < 4; ++j)
        acc[i][j] = __builtin_amdgcn_mfma_f32_16x16x32_bf16(af[i], bf[j], acc[i][j], 0, 0, 0);
    __syncthreads();
  }

#pragma unroll
  for (int i = 0; i < 4; ++i) {
#pragma unroll
    for (int j = 0; j < 4; ++j) {
      if (EPI == 1) {
#pragma unroll
        for (int r = 0; r < 4; ++r) {
          const int m = m0 + wm + i * 16 + lq * 4 + r;
          const int n = n0 + wn + j * 16 + l15;
          outf[(long)m * D_MODEL + n] = acc[i][j][r];
        }
      } else {
        const int n = n0 + wn + j * 16 + l15;       // sel uniform over wave (16-aligned base)
        const int sel = n >> 10, nl = n & 1023;
        const int hh = nl >> 6, dd = nl & 63;
        const int mb = m0 + wm + i * 16 + lq * 4;   // 4 consecutive t
        const int bb = mb >> 11, t0 = mb & (SEQ - 1);
        const long bh = (long)bb * NH + hh;
        if (sel == 2) {
          short4v pk;
#pragma unroll
          for (int r = 0; r < 4; ++r) pk[r] = (short)f2bf(acc[i][j][r]);
          *(short4v*)(vt + (bh * HD + dd) * SEQ + t0) = pk;   // V^T: [bh][d][t]
        } else {
          unsigned short* dst = (sel == 0) ? q : k2;
          const float sgn = (dd & 1) ? 1.f : -1.f;
          const int jt = dd >> 1;
#pragma unroll
          for (int r = 0; r < 4; ++r) {
            const float val = acc[i][j][r];
            const float p = __shfl_xor(val, 1);     // RoPE pair partner (n^1)
            const int t = t0 + r;
            const float c = cosT[t * 32 + jt];
            const float s = sinT[t * 32 + jt];
            dst[((bh * SEQ + t) << 6) + dd] = f2bf(val * c + sgn * s * p);
          }
        }
      }
    }
  }
}

// ---------------------------------------------------------------------------
// K4: causal flash attention, swapped-operand form.
// Block = 4 independent waves; wave = 16 q rows, KV tile = 64.
// S^T = mfma(A=K, B=Q): lane(l15,lq) holds S[q=l15][kv=i*16+lq*4+r].
// Softmax: per-lane m/l scalars (q = l15); reduce = in-reg + shfl_xor(16,32).
// P -> LDS (XOR-swizzled) -> B-frag; O^T = mfma(A=V^T, B=P): col = q = l15.
// ---------------------------------------------------------------------------
template<bool MASK>
static __device__ __forceinline__ void attn_tile(
    const unsigned short* __restrict__ Kp, const unsigned short* __restrict__ Vp,
    unsigned short* __restrict__ Pw, int kv0, int qrow0, int l15, int lq,
    const short8 bq0, const short8 bq1, f32x4 ot[4], float& m, float& lsum) {
  const f32x4 fz = {0.f, 0.f, 0.f, 0.f};
  f32x4 st[4];
  __builtin_amdgcn_s_setprio(1);
#pragma unroll
  for (int i = 0; i < 4; ++i) {
    const unsigned short* kr = Kp + ((long)(kv0 + i * 16 + l15) << 6) + lq * 8;
    const short8 ak0 = *(const short8*)(kr);
    const short8 ak1 = *(const short8*)(kr + 32);
    f32x4 s = fz;
    s = __builtin_amdgcn_mfma_f32_16x16x32_bf16(ak0, bq0, s, 0, 0, 0);
    s = __builtin_amdgcn_mfma_f32_16x16x32_bf16(ak1, bq1, s, 0, 0, 0);
    st[i] = s;
  }
  __builtin_amdgcn_s_setprio(0);

  float tmax = -INFINITY;
#pragma unroll
  for (int i = 0; i < 4; ++i)
#pragma unroll
    for (int r = 0; r < 4; ++r) {
      float vv = st[i][r] * 0.125f;
      if (MASK) { if (kv0 + i * 16 + lq * 4 + r > qrow0 + l15) vv = -INFINITY; }
      st[i][r] = vv;
      tmax = fmaxf(tmax, vv);
    }
  tmax = fmaxf(tmax, __shfl_xor(tmax, 16));
  tmax = fmaxf(tmax, __shfl_xor(tmax, 32));
  const float mn = fmaxf(m, tmax);
  const float al = __expf(m - mn);
  m = mn;
  float rs = 0.f;
#pragma unroll
  for (int i = 0; i < 4; ++i)
#pragma unroll
    for (int r = 0; r < 4; ++r) {
      const float p = __expf(st[i][r] - mn);
      st[i][r] = p;
      rs += p;
    }
  rs += __shfl_xor(rs, 16);
  rs += __shfl_xor(rs, 32);
  lsum = lsum * al + rs;
#pragma unroll
  for (int d = 0; d < 4; ++d)
#pragma unroll
    for (int r = 0; r < 4; ++r) ot[d][r] *= al;

  // P[l15][kv] bf16, row = 128B, XOR-swizzled on bits 4-6
  const int swz = (l15 & 7) << 4;
  const int rowb = l15 << 7;
#pragma unroll
  for (int i = 0; i < 4; ++i) {
    short4v pk;
#pragma unroll
    for (int r = 0; r < 4; ++r) pk[r] = (short)f2bf(st[i][r]);
    *(short4v*)((char*)Pw + ((rowb + (i << 5) + (lq << 3)) ^ swz)) = pk;
  }
  const short8 bp0 = *(const short8*)((char*)Pw + ((rowb + (lq << 4)) ^ swz));
  const short8 bp1 = *(const short8*)((char*)Pw + ((rowb + 64 + (lq << 4)) ^ swz));

  __builtin_amdgcn_s_setprio(1);
#pragma unroll
  for (int db = 0; db < 4; ++db) {
    const unsigned short* vr = Vp + (long)(db * 16 + l15) * SEQ + kv0 + lq * 8;
    const short8 av0 = *(const short8*)(vr);
    const short8 av1 = *(const short8*)(vr + 32);
    ot[db] = __builtin_amdgcn_mfma_f32_16x16x32_bf16(av0, bp0, ot[db], 0, 0, 0);
    ot[db] = __builtin_amdgcn_mfma_f32_16x16x32_bf16(av1, bp1, ot[db], 0, 0, 0);
  }
  __builtin_amdgcn_s_setprio(0);
}

__global__ __launch_bounds__(256) void k_attn(
    const unsigned short* __restrict__ qb, const unsigned short* __restrict__ kb,
    const unsigned short* __restrict__ vt, unsigned short* __restrict__ ctx) {
  __shared__ __align__(16) unsigned short P[4][16 * 64];
  const int wid = threadIdx.x >> 6, lane = threadIdx.x & 63;
  const int l15 = lane & 15, lq = lane >> 4;
  const int bh = blockIdx.y, b = bh >> 4, h = bh & 15;
  const int qrow0 = blockIdx.x * 64 + wid * 16;

  // Q as B-fragment: lane holds Q[q=l15][d = lq*8+j]
  const unsigned short* Qp = qb + (((long)bh * SEQ + qrow0) << 6);
  const short8 bq0 = *(const short8*)(Qp + l15 * HD + lq * 8);
  const short8 bq1 = *(const short8*)(Qp + l15 * HD + 32 + lq * 8);

  const unsigned short* Kp = kb + ((long)bh * SEQ << 6);
  const unsigned short* Vp = vt + (long)bh * HD * SEQ;
  unsigned short* Pw = P[wid];

  const f32x4 fz = {0.f, 0.f, 0.f, 0.f};
  f32x4 ot[4] = {fz, fz, fz, fz};   // O^T frags: row d = db*16+lq*4+r, col q = l15
  float m = -INFINITY, lsum = 0.f;

  const int nfull = qrow0 >> 6;
  for (int tkv = 0; tkv < nfull; ++tkv)
    attn_tile<false>(Kp, Vp, Pw, tkv << 6, qrow0, l15, lq, bq0, bq1, ot, m, lsum);
  attn_tile<true>(Kp, Vp, Pw, nfull << 6, qrow0, l15, lq, bq0, bq1, ot, m, lsum);

  const float inv = 1.0f / lsum;
  unsigned short* cb = ctx + (((long)b * SEQ) << 10) + (h << 6);
  const long t = qrow0 + l15;
#pragma unroll
  for (int db = 0; db < 4; ++db) {
    short4v pk;
#pragma unroll
    for (int r = 0; r < 4; ++r) pk[r] = (short)f2bf(ot[db][r] * inv);
    *(short4v*)(cb + t * D_MODEL + db * 16 + lq * 4) = pk;
  }
}

// ---------------------------------------------------------------------------
extern "C" void kernel_launch(void* const* d_in, const int* in_sizes, int n_in,
                              void* d_out, int out_size, void* d_ws, size_t ws_size,
                              hipStream_t stream) {
  const float* x  = (const float*)d_in[0];
  const float* wq = (const float*)d_in[1];
  const float* wk = (const float*)d_in[2];
  const float* wv = (const float*)d_in[3];
  const float* wo = (const float*)d_in[4];
  float* out = (float*)d_out;
  char* ws = (char*)d_ws;

  unsigned short* xb  = (unsigned short*)(ws);                 // 16 MB (x bf16; reused as ctx)
  unsigned short* wb  = (unsigned short*)(ws + (16l << 20));   // 8 MB  (Wq|Wk|Wv|Wo bf16)
  unsigned short* qb  = (unsigned short*)(ws + (24l << 20));   // 16 MB [bh][t][d]
  unsigned short* kb  = (unsigned short*)(ws + (40l << 20));   // 16 MB [bh][t][d]
  unsigned short* vt  = (unsigned short*)(ws + (56l << 20));   // 16 MB [bh][d][t]
  float* cosT = (float*)(ws + (72l << 20));                    // 256 KB
  float* sinT = cosT + SEQ * 32;                               // 256 KB
  unsigned short* ctx = xb;   // xb dead after QKV GEMM

  const long ntot = (long)MTOT * D_MODEL + 4l * D_MODEL * D_MODEL + (long)SEQ * 32;
  k_prep<<<dim3((unsigned)((ntot + 255) / 256)), dim3(256), 0, stream>>>(
      x, wq, wk, wv, wo, xb, wb, cosT, sinT);
  k_gemm<0><<<dim3(64, 24), dim3(256), 0, stream>>>(
      xb, wb, qb, kb, vt, cosT, sinT, nullptr);
  k_attn<<<dim3(32, 64), dim3(256), 0, stream>>>(qb, kb, vt, ctx);
  k_gemm<1><<<dim3(64, 8), dim3(256), 0, stream>>>(
      ctx, wb + 3l * D_MODEL * D_MODEL, nullptr, nullptr, nullptr, nullptr, nullptr, out);
}

// Round 3
// 243.069 us; speedup vs baseline: 2.3882x; 2.3882x over previous
//
#include <hip/hip_runtime.h>
#include <hip/hip_bf16.h>
#include <stdint.h>
#include <math.h>

#define D_MODEL 1024
#define NH 16
#define HD 64
#define BATCH 4
#define SEQ 2048
#define MTOT (BATCH*SEQ)   // 8192
#define NBH (BATCH*NH)     // 64

typedef __attribute__((ext_vector_type(8))) short short8;   // 8 bf16
typedef __attribute__((ext_vector_type(4))) short short4v;  // 4 bf16
typedef __attribute__((ext_vector_type(4))) float f32x4;

static __device__ __forceinline__ unsigned short f2bf(float f) {
  union { float f; unsigned u; } v; v.f = f;
  unsigned r = v.u + 0x7FFFu + ((v.u >> 16) & 1u);   // RNE
  return (unsigned short)(r >> 16);
}

static __device__ __forceinline__ float fexp2(float x) {
#if __has_builtin(__builtin_amdgcn_exp2f)
  return __builtin_amdgcn_exp2f(x);
#else
  return __expf(x * 0.69314718056f);
#endif
}

#define GLOAD16(g, l) __builtin_amdgcn_global_load_lds( \
    (const __attribute__((address_space(1))) unsigned int*)(g), \
    (__attribute__((address_space(3))) unsigned int*)(l), 16, 0, 0)

// ---------------------------------------------------------------------------
// K0: convert x and weights to bf16, build RoPE tables
// ---------------------------------------------------------------------------
__global__ __launch_bounds__(256) void k_prep(
    const float* __restrict__ x, const float* __restrict__ wq,
    const float* __restrict__ wk, const float* __restrict__ wv,
    const float* __restrict__ wo,
    unsigned short* __restrict__ xb, unsigned short* __restrict__ wb,
    float* __restrict__ cosT, float* __restrict__ sinT) {
  long i = (long)blockIdx.x * 256 + threadIdx.x;
  const long NX = (long)MTOT * D_MODEL;
  const long NW = (long)D_MODEL * D_MODEL;
  if (i < NX) { xb[i] = f2bf(x[i]); return; }
  i -= NX;
  if (i < NW) { wb[i] = f2bf(wq[i]); return; }
  i -= NW;
  if (i < NW) { wb[NW + i] = f2bf(wk[i]); return; }
  i -= NW;
  if (i < NW) { wb[2 * NW + i] = f2bf(wv[i]); return; }
  i -= NW;
  if (i < NW) { wb[3 * NW + i] = f2bf(wo[i]); return; }
  i -= NW;
  if (i < (long)SEQ * (HD / 2)) {
    int t = (int)(i >> 5), j = (int)(i & 31);
    float freq = 1.0f / powf(10000.0f, (float)j * (1.0f / 32.0f));
    float ang = (float)t * freq;
    cosT[i] = cosf(ang);
    sinT[i] = sinf(ang);
  }
}

// ---------------------------------------------------------------------------
// GEMM: C[m][n] = sum_k A[m][k] * Bw[n][k]
// EPI=0 (QKV): RoPE fused for q/k (q additionally scaled by 0.125*log2e),
// scatter q/k to [bh][t][d]; V stored transposed to vt [bh][d][t].
// EPI=1: fp32 out [m][n].
// ---------------------------------------------------------------------------
template<int EPI>
__global__ __launch_bounds__(256) void k_gemm(
    const unsigned short* __restrict__ A, const unsigned short* __restrict__ Bw,
    unsigned short* __restrict__ q, unsigned short* __restrict__ k2,
    unsigned short* __restrict__ vt,
    const float* __restrict__ cosT, const float* __restrict__ sinT,
    float* __restrict__ outf) {
  __shared__ __align__(16) unsigned short As[128 * 32];
  __shared__ __align__(16) unsigned short Bs[128 * 32];
  const int tid = threadIdx.x;
  const int wid = tid >> 6, lane = tid & 63;
  const int l15 = lane & 15, lq = lane >> 4;
  const int m0 = blockIdx.x * 128, n0 = blockIdx.y * 128;
  const int wm = (wid >> 1) * 64, wn = (wid & 1) * 64;

  const f32x4 fz = {0.f, 0.f, 0.f, 0.f};
  f32x4 acc[4][4];
#pragma unroll
  for (int i = 0; i < 4; ++i)
#pragma unroll
    for (int j = 0; j < 4; ++j) acc[i][j] = fz;

  const int srow = wid * 16 + (lane >> 2);
  const int scol = (lane & 3) * 8;
  const unsigned short* Ag = A + (long)(m0 + srow) * D_MODEL + scol;
  const unsigned short* Bg = Bw + (long)(n0 + srow) * D_MODEL + scol;

  for (int k0 = 0; k0 < D_MODEL; k0 += 32) {
    GLOAD16(Ag + k0, As + wid * 512);
    GLOAD16(Ag + k0 + 64 * D_MODEL, As + 2048 + wid * 512);
    GLOAD16(Bg + k0, Bs + wid * 512);
    GLOAD16(Bg + k0 + 64 * D_MODEL, Bs + 2048 + wid * 512);
    __syncthreads();

    short8 af[4], bf[4];
#pragma unroll
    for (int i = 0; i < 4; ++i) {
      af[i] = *(const short8*)(As + (wm + i * 16 + l15) * 32 + lq * 8);
      bf[i] = *(const short8*)(Bs + (wn + i * 16 + l15) * 32 + lq * 8);
    }
#pragma unroll
    for (int i = 0; i < 4; ++i)
#pragma unroll
      for (int j = 0; j < 4; ++j)
        acc[i][j] = __builtin_amdgcn_mfma_f32_16x16x32_bf16(af[i], bf[j], acc[i][j], 0, 0, 0);
    __syncthreads();
  }

#pragma unroll
  for (int i = 0; i < 4; ++i) {
#pragma unroll
    for (int j = 0; j < 4; ++j) {
      if (EPI == 1) {
#pragma unroll
        for (int r = 0; r < 4; ++r) {
          const int m = m0 + wm + i * 16 + lq * 4 + r;
          const int n = n0 + wn + j * 16 + l15;
          outf[(long)m * D_MODEL + n] = acc[i][j][r];
        }
      } else {
        const int n = n0 + wn + j * 16 + l15;       // sel uniform over wave
        const int sel = n >> 10, nl = n & 1023;
        const int hh = nl >> 6, dd = nl & 63;
        const int mb = m0 + wm + i * 16 + lq * 4;   // 4 consecutive t
        const int bb = mb >> 11, t0 = mb & (SEQ - 1);
        const long bh = (long)bb * NH + hh;
        if (sel == 2) {
          short4v pk;
#pragma unroll
          for (int r = 0; r < 4; ++r) pk[r] = (short)f2bf(acc[i][j][r]);
          *(short4v*)(vt + (bh * HD + dd) * SEQ + t0) = pk;   // V^T: [bh][d][t]
        } else {
          unsigned short* dst = (sel == 0) ? q : k2;
          const float qs = (sel == 0) ? 0.18033688011112793f : 1.0f;  // 0.125*log2e
          const float sgn = (dd & 1) ? 1.f : -1.f;
          const int jt = dd >> 1;
#pragma unroll
          for (int r = 0; r < 4; ++r) {
            const float val = acc[i][j][r];
            const float p = __shfl_xor(val, 1);     // RoPE pair partner (n^1)
            const int t = t0 + r;
            const float c = cosT[t * 32 + jt];
            const float s = sinT[t * 32 + jt];
            dst[((bh * SEQ + t) << 6) + dd] = f2bf((val * c + sgn * s * p) * qs);
          }
        }
      }
    }
  }
}

// ---------------------------------------------------------------------------
// K4: causal flash attention, swapped-operand, LDS-staged K/V (2-phase dbuf).
// Block = 4 waves x 32 q-rows = 128 q-rows; KV tile = 64.
// K/V tiles staged via global_load_lds with pre-swizzled source (chunk^=row&7);
// all ds_read_b128 conflict-free. Two q-streams per wave share K/V A-frags.
// Scores arrive pre-scaled by 0.125*log2e -> softmax uses exp2.
// ---------------------------------------------------------------------------
static __device__ __forceinline__ void softmax_pack(
    f32x4 st[4], float& m, float& lsum, f32x4 ot[4],
    unsigned short* Pst, const int l15, const int lq,
    const bool msk, const int kv0, const int qg,
    short8& bp0, short8& bp1) {
  if (msk) {
#pragma unroll
    for (int i = 0; i < 4; ++i)
#pragma unroll
      for (int r = 0; r < 4; ++r)
        if (kv0 + i * 16 + lq * 4 + r > qg) st[i][r] = -INFINITY;
  }
  float tmax = st[0][0];
#pragma unroll
  for (int i = 0; i < 4; ++i)
#pragma unroll
    for (int r = 0; r < 4; ++r) tmax = fmaxf(tmax, st[i][r]);
  tmax = fmaxf(tmax, __shfl_xor(tmax, 16));
  tmax = fmaxf(tmax, __shfl_xor(tmax, 32));
  const float mn = fmaxf(m, tmax);
  const float al = fexp2(m - mn);
  m = mn;
  float rs = 0.f;
#pragma unroll
  for (int i = 0; i < 4; ++i)
#pragma unroll
    for (int r = 0; r < 4; ++r) {
      const float p = fexp2(st[i][r] - mn);
      st[i][r] = p;
      rs += p;
    }
  rs += __shfl_xor(rs, 16);
  rs += __shfl_xor(rs, 32);
  lsum = lsum * al + rs;
#pragma unroll
  for (int d = 0; d < 4; ++d) ot[d] *= al;

  const int sw4 = (l15 & 7) << 4;
  char* rowp = (char*)Pst + (l15 << 7);
#pragma unroll
  for (int i = 0; i < 4; ++i) {
    short4v pk;
#pragma unroll
    for (int r = 0; r < 4; ++r) pk[r] = (short)f2bf(st[i][r]);
    *(short4v*)(rowp + (((i << 5) + (lq << 3)) ^ sw4)) = pk;
  }
  bp0 = *(const short8*)(rowp + ((lq << 4) ^ sw4));
  bp1 = *(const short8*)(rowp + (((lq + 4) << 4) ^ sw4));
}

__global__ __launch_bounds__(256, 3) void k_attn(
    const unsigned short* __restrict__ qb, const unsigned short* __restrict__ kb,
    const unsigned short* __restrict__ vt, unsigned short* __restrict__ ctx) {
  __shared__ __align__(16) unsigned short Ks[2][4096];   // [64 kv][64 d] swizzled
  __shared__ __align__(16) unsigned short Vs[2][4096];   // [64 d][64 kv] swizzled
  __shared__ __align__(16) unsigned short Ps[4][2048];   // per-wave P, 2 streams

  // XCD-clustered + LPT block remap: each XCD owns 8 contiguous bh; longest
  // blocks (most kv tiles) dispatch first.
  const int orig = blockIdx.x;                 // 0..1023
  const int swz = (orig & 7) * 128 + (orig >> 3);
  const int bh = swz >> 4;
  const int blk = 15 - (swz & 15);
  const int nt = 2 * blk + 2;

  const int tid = threadIdx.x;
  const int wid = tid >> 6, lane = tid & 63;
  const int l15 = lane & 15, lq = lane >> 4;
  const int qrow0w = blk * 128 + wid * 32;

  const unsigned short* Kg = kb + ((long)bh * SEQ << 6);
  const unsigned short* Vg = vt + (long)bh * HD * SEQ;

  // staging geometry (constant per thread): granule g0=tid (rows 0..31),
  // g1=tid+256 (rows 32..63); source chunk pre-swizzled so LDS is read-swizzled
  const int r0 = tid >> 3, c0 = tid & 7;
  const int r1 = r0 + 32;
  const int cs = c0 ^ (r0 & 7);                // r1&7 == r0&7

  // Q fragments, two streams (q rows qrow0w+l15 and +16+l15)
  const unsigned short* Qp = qb + (((long)bh * SEQ + qrow0w) << 6);
  const short8 bqA0 = *(const short8*)(Qp + l15 * HD + lq * 8);
  const short8 bqA1 = *(const short8*)(Qp + l15 * HD + 32 + lq * 8);
  const short8 bqB0 = *(const short8*)(Qp + ((16 + l15) << 6) + lq * 8);
  const short8 bqB1 = *(const short8*)(Qp + ((16 + l15) << 6) + 32 + lq * 8);

  const f32x4 fz = {0.f, 0.f, 0.f, 0.f};
  f32x4 otA[4] = {fz, fz, fz, fz}, otB[4] = {fz, fz, fz, fz};
  float mA = -INFINITY, mB = -INFINITY, lA = 0.f, lB = 0.f;

#define STAGE(t_) { \
    const long kv0s = (long)((t_) << 6); \
    unsigned short* kd = Ks[(t_) & 1]; \
    unsigned short* vd = Vs[(t_) & 1]; \
    GLOAD16(Kg + ((kv0s + r0) << 6) + (cs << 3), kd + wid * 512); \
    GLOAD16(Kg + ((kv0s + r1) << 6) + (cs << 3), kd + 2048 + wid * 512); \
    GLOAD16(Vg + (long)r0 * SEQ + kv0s + (cs << 3), vd + wid * 512); \
    GLOAD16(Vg + (long)r1 * SEQ + kv0s + (cs << 3), vd + 2048 + wid * 512); \
  }

  STAGE(0);
  __syncthreads();

  const int sw4 = (l15 & 7) << 4;
  for (int t = 0; t < nt; ++t) {
    const int kv0 = t << 6;
    if (t + 1 < nt) STAGE(t + 1);

    const bool actA = kv0 <= qrow0w + 15;
    const bool actB = kv0 <= qrow0w + 31;
    if (actB) {
      const char* Kb = (const char*)Ks[t & 1];
      const char* Vb = (const char*)Vs[t & 1];
      f32x4 sA[4], sB[4];
#pragma unroll
      for (int i = 0; i < 4; ++i) { sA[i] = fz; sB[i] = fz; }

      __builtin_amdgcn_s_setprio(1);
#pragma unroll
      for (int i = 0; i < 4; ++i) {
        const int rowb = (i * 16 + l15) << 7;
        const short8 ak0 = *(const short8*)(Kb + rowb + ((lq << 4) ^ sw4));
        const short8 ak1 = *(const short8*)(Kb + rowb + (((lq + 4) << 4) ^ sw4));
        if (actA) {
          sA[i] = __builtin_amdgcn_mfma_f32_16x16x32_bf16(ak0, bqA0, sA[i], 0, 0, 0);
          sA[i] = __builtin_amdgcn_mfma_f32_16x16x32_bf16(ak1, bqA1, sA[i], 0, 0, 0);
        }
        sB[i] = __builtin_amdgcn_mfma_f32_16x16x32_bf16(ak0, bqB0, sB[i], 0, 0, 0);
        sB[i] = __builtin_amdgcn_mfma_f32_16x16x32_bf16(ak1, bqB1, sB[i], 0, 0, 0);
      }
      __builtin_amdgcn_s_setprio(0);

      const bool mskA = kv0 + 63 > qrow0w;
      const bool mskB = kv0 + 63 > qrow0w + 16;
      short8 bpA0, bpA1, bpB0, bpB1;
      if (actA)
        softmax_pack(sA, mA, lA, otA, &Ps[wid][0], l15, lq, mskA, kv0,
                     qrow0w + l15, bpA0, bpA1);
      softmax_pack(sB, mB, lB, otB, &Ps[wid][1024], l15, lq, mskB, kv0,
                   qrow0w + 16 + l15, bpB0, bpB1);

      __builtin_amdgcn_s_setprio(1);
#pragma unroll
      for (int db = 0; db < 4; ++db) {
        const int rowb = (db * 16 + l15) << 7;
        const short8 av0 = *(const short8*)(Vb + rowb + ((lq << 4) ^ sw4));
        const short8 av1 = *(const short8*)(Vb + rowb + (((lq + 4) << 4) ^ sw4));
        if (actA) {
          otA[db] = __builtin_amdgcn_mfma_f32_16x16x32_bf16(av0, bpA0, otA[db], 0, 0, 0);
          otA[db] = __builtin_amdgcn_mfma_f32_16x16x32_bf16(av1, bpA1, otA[db], 0, 0, 0);
        }
        otB[db] = __builtin_amdgcn_mfma_f32_16x16x32_bf16(av0, bpB0, otB[db], 0, 0, 0);
        otB[db] = __builtin_amdgcn_mfma_f32_16x16x32_bf16(av1, bpB1, otB[db], 0, 0, 0);
      }
      __builtin_amdgcn_s_setprio(0);
    }
    __syncthreads();
  }
#undef STAGE

  const int b = bh >> 4, h = bh & 15;
  unsigned short* cb = ctx + (((long)b * SEQ) << 10) + (h << 6);
  {
    const float inv = 1.0f / lA;
    const long t = qrow0w + l15;
#pragma unroll
    for (int db = 0; db < 4; ++db) {
      short4v pk;
#pragma unroll
      for (int r = 0; r < 4; ++r) pk[r] = (short)f2bf(otA[db][r] * inv);
      *(short4v*)(cb + t * D_MODEL + db * 16 + lq * 4) = pk;
    }
  }
  {
    const float inv = 1.0f / lB;
    const long t = qrow0w + 16 + l15;
#pragma unroll
    for (int db = 0; db < 4; ++db) {
      short4v pk;
#pragma unroll
      for (int r = 0; r < 4; ++r) pk[r] = (short)f2bf(otB[db][r] * inv);
      *(short4v*)(cb + t * D_MODEL + db * 16 + lq * 4) = pk;
    }
  }
}

// ---------------------------------------------------------------------------
extern "C" void kernel_launch(void* const* d_in, const int* in_sizes, int n_in,
                              void* d_out, int out_size, void* d_ws, size_t ws_size,
                              hipStream_t stream) {
  const float* x  = (const float*)d_in[0];
  const float* wq = (const float*)d_in[1];
  const float* wk = (const float*)d_in[2];
  const float* wv = (const float*)d_in[3];
  const float* wo = (const float*)d_in[4];
  float* out = (float*)d_out;
  char* ws = (char*)d_ws;

  unsigned short* xb  = (unsigned short*)(ws);                 // 16 MB (x bf16; reused as ctx)
  unsigned short* wb  = (unsigned short*)(ws + (16l << 20));   // 8 MB  (Wq|Wk|Wv|Wo bf16)
  unsigned short* qb  = (unsigned short*)(ws + (24l << 20));   // 16 MB [bh][t][d]
  unsigned short* kb  = (unsigned short*)(ws + (40l << 20));   // 16 MB [bh][t][d]
  unsigned short* vt  = (unsigned short*)(ws + (56l << 20));   // 16 MB [bh][d][t]
  float* cosT = (float*)(ws + (72l << 20));                    // 256 KB
  float* sinT = cosT + SEQ * 32;                               // 256 KB
  unsigned short* ctx = xb;   // xb dead after QKV GEMM

  const long ntot = (long)MTOT * D_MODEL + 4l * D_MODEL * D_MODEL + (long)SEQ * 32;
  k_prep<<<dim3((unsigned)((ntot + 255) / 256)), dim3(256), 0, stream>>>(
      x, wq, wk, wv, wo, xb, wb, cosT, sinT);
  k_gemm<0><<<dim3(64, 24), dim3(256), 0, stream>>>(
      xb, wb, qb, kb, vt, cosT, sinT, nullptr);
  k_attn<<<dim3(1024), dim3(256), 0, stream>>>(qb, kb, vt, ctx);
  k_gemm<1><<<dim3(64, 8), dim3(256), 0, stream>>>(
      ctx, wb + 3l * D_MODEL * D_MODEL, nullptr, nullptr, nullptr, nullptr, nullptr, out);
}